// Round 1
// baseline (340.570 us; speedup 1.0000x reference)
//
#include <hip/hip_runtime.h>

// Problem constants (fixed by the reference).
#define BS 64
#define DX 512
#define DY 512
#define L (DX * DY)                 // 262144 bins per sample
#define TILE 4096                   // elements per tile
#define T_PER_S (L / TILE)          // 64 tiles per sample
#define THREADS 256
#define EPT (TILE / THREADS)        // 16 elements per thread (contiguous chunk)

// ---------------------------------------------------------------------------
// Phase 1: per-tile nonzero counts.
// Grid: BS*T_PER_S blocks. Each thread owns a contiguous 16-elem chunk
// (4x float4) — same layout as the compact kernel for consistency.
// ---------------------------------------------------------------------------
__global__ __launch_bounds__(THREADS) void htpc_count(
    const float* __restrict__ hist, int* __restrict__ tile_count) {
  const int tile = blockIdx.x;
  const size_t base = (size_t)tile * TILE + (size_t)threadIdx.x * EPT;
  const float4* h4 = (const float4*)(hist + base);

  int cnt = 0;
#pragma unroll
  for (int i = 0; i < EPT / 4; ++i) {
    float4 v = h4[i];
    cnt += (v.x != 0.f) + (v.y != 0.f) + (v.z != 0.f) + (v.w != 0.f);
  }
  // wave reduce (wave = 64)
  const int lane = threadIdx.x & 63;
  const int wv = threadIdx.x >> 6;
#pragma unroll
  for (int d = 32; d > 0; d >>= 1) cnt += __shfl_down(cnt, d);
  __shared__ int ws[THREADS / 64];
  if (lane == 0) ws[wv] = cnt;
  __syncthreads();
  if (threadIdx.x == 0) {
    int s = 0;
#pragma unroll
    for (int i = 0; i < THREADS / 64; ++i) s += ws[i];
    tile_count[tile] = s;
  }
}

// ---------------------------------------------------------------------------
// Phase 2: per-sample exclusive scan over T_PER_S=64 tile counts (one wave
// per sample), emit per-tile base offsets and lens[b] (stored as float — the
// harness reads the entire concatenated output buffer as float32).
// ---------------------------------------------------------------------------
__global__ __launch_bounds__(64) void htpc_scan(
    const int* __restrict__ tile_count, int* __restrict__ tile_off,
    float* __restrict__ out_lens) {
  const int b = blockIdx.x;
  const int t = threadIdx.x;  // 0..63
  const int c = tile_count[b * T_PER_S + t];
  int incl = c;
#pragma unroll
  for (int d = 1; d < 64; d <<= 1) {
    int n = __shfl_up(incl, d);
    if (t >= d) incl += n;
  }
  tile_off[b * T_PER_S + t] = incl - c;  // exclusive
  if (t == 63) out_lens[b] = (float)incl;  // total nonzeros in sample b
}

// ---------------------------------------------------------------------------
// Phase 3: stable compaction. Each block re-reads its tile, block-exclusive-
// scans the per-thread nonzero counts (thread chunks are contiguous, so
// thread-order == row-major order => stable), then scatters (cx,cy) pairs
// and weights at tile_off + rank.
// ---------------------------------------------------------------------------
__global__ __launch_bounds__(THREADS) void htpc_compact(
    const float* __restrict__ hist, const float* __restrict__ x_lims,
    const float* __restrict__ y_lims, const int* __restrict__ tile_off,
    float* __restrict__ out_pc, float* __restrict__ out_w) {
  const int tile = blockIdx.x;
  const int b = tile / T_PER_S;
  const size_t gbase = (size_t)tile * TILE + (size_t)threadIdx.x * EPT;
  const float4* h4 = (const float4*)(hist + gbase);

  float v[EPT];
#pragma unroll
  for (int i = 0; i < EPT / 4; ++i) {
    float4 a = h4[i];
    v[i * 4 + 0] = a.x;
    v[i * 4 + 1] = a.y;
    v[i * 4 + 2] = a.z;
    v[i * 4 + 3] = a.w;
  }
  int cnt = 0;
#pragma unroll
  for (int i = 0; i < EPT; ++i) cnt += (v[i] != 0.f);

  // block exclusive scan over 256 thread counts (4 waves)
  const int lane = threadIdx.x & 63;
  const int wv = threadIdx.x >> 6;
  int incl = cnt;
#pragma unroll
  for (int d = 1; d < 64; d <<= 1) {
    int n = __shfl_up(incl, d);
    if (lane >= d) incl += n;
  }
  __shared__ int wsum[THREADS / 64];
  if (lane == 63) wsum[wv] = incl;
  __syncthreads();
  int wbase = 0;
#pragma unroll
  for (int i = 0; i < THREADS / 64; ++i)
    if (i < wv) wbase += wsum[i];
  int pos = tile_off[tile] + wbase + (incl - cnt);  // global rank in sample b

  // center-grid parameters: cx[j] = xlo + cxw*(j + 0.5)
  const float xlo = x_lims[b * 2], xhi = x_lims[b * 2 + 1];
  const float ylo = y_lims[b * 2], yhi = y_lims[b * 2 + 1];
  const float cxw = (xhi - xlo) / DX;
  const float cyw = (yhi - ylo) / DY;

  const int lidx0 = (int)(gbase - (size_t)b * L);  // index within sample
  float* pc = out_pc + (size_t)b * L * 2;
  float* w = out_w + (size_t)b * L;

#pragma unroll
  for (int i = 0; i < EPT; ++i) {
    if (v[i] != 0.f) {
      const int idx = lidx0 + i;
      const int ix = idx >> 9;   // idx / DY
      const int iy = idx & 511;  // idx % DY
      pc[(size_t)pos * 2 + 0] = xlo + cxw * ((float)ix + 0.5f);
      pc[(size_t)pos * 2 + 1] = ylo + cyw * ((float)iy + 0.5f);
      w[pos] = v[i];
      ++pos;
    }
  }
}

extern "C" void kernel_launch(void* const* d_in, const int* in_sizes, int n_in,
                              void* d_out, int out_size, void* d_ws,
                              size_t ws_size, hipStream_t stream) {
  const float* hist = (const float*)d_in[0];    // [BS, DX, DY]
  const float* x_lims = (const float*)d_in[1];  // [BS, 2]
  const float* y_lims = (const float*)d_in[2];  // [BS, 2]

  float* out = (float*)d_out;
  float* out_pc = out;                          // [BS, L, 2]
  float* out_w = out + (size_t)BS * L * 2;      // [BS, L]
  float* out_lens = out_w + (size_t)BS * L;     // [BS] (as float32)

  int* tile_count = (int*)d_ws;                 // [BS * T_PER_S]
  int* tile_off = tile_count + BS * T_PER_S;    // [BS * T_PER_S]

  // Tails of the compacted outputs must be zero; zero everything first.
  hipMemsetAsync(d_out, 0, (size_t)out_size * sizeof(float), stream);

  htpc_count<<<BS * T_PER_S, THREADS, 0, stream>>>(hist, tile_count);
  htpc_scan<<<BS, 64, 0, stream>>>(tile_count, tile_off, out_lens);
  htpc_compact<<<BS * T_PER_S, THREADS, 0, stream>>>(hist, x_lims, y_lims,
                                                     tile_off, out_pc, out_w);
}

// Round 2
// 259.201 us; speedup vs baseline: 1.3139x; 1.3139x over previous
//
#include <hip/hip_runtime.h>

// Problem constants (fixed by the reference).
#define BS 64
#define DX 512
#define DY 512
#define L (DX * DY)                 // 262144 bins per sample
#define TILE 4096                   // elements per tile
#define T_PER_S (L / TILE)          // 64 tiles per sample
#define THREADS 256
#define EPT (TILE / THREADS)        // 16 elements per thread (contiguous chunk)

// ---------------------------------------------------------------------------
// Phase 1: per-tile nonzero counts.
// ---------------------------------------------------------------------------
__global__ __launch_bounds__(THREADS) void htpc_count(
    const float* __restrict__ hist, int* __restrict__ tile_count) {
  const int tile = blockIdx.x;
  const size_t base = (size_t)tile * TILE + (size_t)threadIdx.x * EPT;
  const float4* h4 = (const float4*)(hist + base);

  int cnt = 0;
#pragma unroll
  for (int i = 0; i < EPT / 4; ++i) {
    float4 v = h4[i];
    cnt += (v.x != 0.f) + (v.y != 0.f) + (v.z != 0.f) + (v.w != 0.f);
  }
  const int lane = threadIdx.x & 63;
  const int wv = threadIdx.x >> 6;
#pragma unroll
  for (int d = 32; d > 0; d >>= 1) cnt += __shfl_down(cnt, d);
  __shared__ int ws[THREADS / 64];
  if (lane == 0) ws[wv] = cnt;
  __syncthreads();
  if (threadIdx.x == 0) {
    int s = 0;
#pragma unroll
    for (int i = 0; i < THREADS / 64; ++i) s += ws[i];
    tile_count[tile] = s;
  }
}

// ---------------------------------------------------------------------------
// Phase 2: per-sample exclusive scan over 64 tile counts (one wave per
// sample). Emits tile base offsets, lens[b] as float (output), and lens[b]
// as int (workspace, for the tail-zero kernel).
// ---------------------------------------------------------------------------
__global__ __launch_bounds__(64) void htpc_scan(
    const int* __restrict__ tile_count, int* __restrict__ tile_off,
    float* __restrict__ out_lens, int* __restrict__ lens_i) {
  const int b = blockIdx.x;
  const int t = threadIdx.x;  // 0..63
  const int c = tile_count[b * T_PER_S + t];
  int incl = c;
#pragma unroll
  for (int d = 1; d < 64; d <<= 1) {
    int n = __shfl_up(incl, d);
    if (t >= d) incl += n;
  }
  tile_off[b * T_PER_S + t] = incl - c;  // exclusive
  if (t == 63) {
    out_lens[b] = (float)incl;
    lens_i[b] = incl;
  }
}

// ---------------------------------------------------------------------------
// Phase 3: stable compaction with LDS staging.
// Each block: read tile, block-scan ranks, stage compacted (x,y) and w into
// LDS, then stream them out with lane-coalesced stores.
// ---------------------------------------------------------------------------
__global__ __launch_bounds__(THREADS) void htpc_compact(
    const float* __restrict__ hist, const float* __restrict__ x_lims,
    const float* __restrict__ y_lims, const int* __restrict__ tile_off,
    float* __restrict__ out_pc, float* __restrict__ out_w) {
  __shared__ float2 spc[TILE];      // 32 KiB
  __shared__ float sw[TILE];        // 16 KiB
  __shared__ int wsum[THREADS / 64];

  const int tile = blockIdx.x;
  const int b = tile / T_PER_S;
  const size_t gbase = (size_t)tile * TILE + (size_t)threadIdx.x * EPT;
  const float4* h4 = (const float4*)(hist + gbase);

  float v[EPT];
#pragma unroll
  for (int i = 0; i < EPT / 4; ++i) {
    float4 a = h4[i];
    v[i * 4 + 0] = a.x;
    v[i * 4 + 1] = a.y;
    v[i * 4 + 2] = a.z;
    v[i * 4 + 3] = a.w;
  }
  int cnt = 0;
#pragma unroll
  for (int i = 0; i < EPT; ++i) cnt += (v[i] != 0.f);

  // block exclusive scan over 256 thread counts (4 waves)
  const int lane = threadIdx.x & 63;
  const int wv = threadIdx.x >> 6;
  int incl = cnt;
#pragma unroll
  for (int d = 1; d < 64; d <<= 1) {
    int n = __shfl_up(incl, d);
    if (lane >= d) incl += n;
  }
  if (lane == 63) wsum[wv] = incl;
  __syncthreads();
  int wbase = 0, total = 0;
#pragma unroll
  for (int i = 0; i < THREADS / 64; ++i) {
    int s = wsum[i];
    if (i < wv) wbase += s;
    total += s;
  }
  int r = wbase + (incl - cnt);  // exclusive rank within tile (stable)

  // center-grid params: cx[j] = xlo + cxw*(j+0.5)
  const float xlo = x_lims[b * 2], xhi = x_lims[b * 2 + 1];
  const float ylo = y_lims[b * 2], yhi = y_lims[b * 2 + 1];
  const float cxw = (xhi - xlo) / DX;
  const float cyw = (yhi - ylo) / DY;

  const int lidx0 = (int)(gbase - (size_t)b * L);  // index within sample

#pragma unroll
  for (int i = 0; i < EPT; ++i) {
    if (v[i] != 0.f) {
      const int idx = lidx0 + i;
      const int ix = idx >> 9;   // idx / DY
      const int iy = idx & 511;  // idx % DY
      spc[r] = make_float2(xlo + cxw * ((float)ix + 0.5f),
                           ylo + cyw * ((float)iy + 0.5f));
      sw[r] = v[i];
      ++r;
    }
  }
  __syncthreads();

  // coalesced streaming writes of the compacted run
  const int off = tile_off[tile];
  float2* pc2 = (float2*)out_pc + (size_t)b * L;  // per-sample base, pair units
  float* w = out_w + (size_t)b * L;
  for (int k = threadIdx.x; k < total; k += THREADS) {
    pc2[off + k] = spc[k];
    w[off + k] = sw[k];
  }
}

// ---------------------------------------------------------------------------
// Phase 4: zero the tails [lens[b], L) of pc (pair units) and w.
// Grid matches the tile decomposition; only tail elements are written.
// ---------------------------------------------------------------------------
__global__ __launch_bounds__(THREADS) void htpc_tail(
    const int* __restrict__ lens_i, float* __restrict__ out_pc,
    float* __restrict__ out_w) {
  const int tile = blockIdx.x;
  const int b = tile / T_PER_S;
  const int t = tile % T_PER_S;
  const int len = lens_i[b];
  const int begin = t * TILE;        // stripe [begin, begin+TILE) in pair/elem units
  if (begin + TILE <= len) return;   // stripe entirely compacted — nothing to zero

  float2* pc2 = (float2*)out_pc + (size_t)b * L;
  float* w = out_w + (size_t)b * L;
  for (int i = begin + threadIdx.x; i < begin + TILE; i += THREADS) {
    if (i >= len) {
      pc2[i] = make_float2(0.f, 0.f);
      w[i] = 0.f;
    }
  }
}

extern "C" void kernel_launch(void* const* d_in, const int* in_sizes, int n_in,
                              void* d_out, int out_size, void* d_ws,
                              size_t ws_size, hipStream_t stream) {
  const float* hist = (const float*)d_in[0];    // [BS, DX, DY]
  const float* x_lims = (const float*)d_in[1];  // [BS, 2]
  const float* y_lims = (const float*)d_in[2];  // [BS, 2]

  float* out = (float*)d_out;
  float* out_pc = out;                          // [BS, L, 2]
  float* out_w = out + (size_t)BS * L * 2;      // [BS, L]
  float* out_lens = out_w + (size_t)BS * L;     // [BS] (as float32)

  int* tile_count = (int*)d_ws;                 // [BS * T_PER_S]
  int* tile_off = tile_count + BS * T_PER_S;    // [BS * T_PER_S]
  int* lens_i = tile_off + BS * T_PER_S;        // [BS]

  htpc_count<<<BS * T_PER_S, THREADS, 0, stream>>>(hist, tile_count);
  htpc_scan<<<BS, 64, 0, stream>>>(tile_count, tile_off, out_lens, lens_i);
  htpc_compact<<<BS * T_PER_S, THREADS, 0, stream>>>(hist, x_lims, y_lims,
                                                     tile_off, out_pc, out_w);
  htpc_tail<<<BS * T_PER_S, THREADS, 0, stream>>>(lens_i, out_pc, out_w);
}